// Round 2
// baseline (1762.163 us; speedup 1.0000x reference)
//
#include <hip/hip_runtime.h>
#include <hip/hip_bf16.h>

#define EPS 1e-5f
typedef __hip_bfloat16 bf;

// Sizes: B=4, C_IN=512, T=4, H=W=K=56, G=8, GP=64, OCH=1024
// NB = B*T*W = 896 ; NP = NB*H = 50176
// ws layout (float offsets for stats; qkv region is bf16)
#define WS_SIMSUM   0            // [24][64]
#define WS_SIMSQ    1536         // [24][64]
#define WS_OUTSUM   3072         // [1024][8]
#define WS_OUTSQ    11264        // [1024][8]
#define WS_ZERO_END 19456
#define WS_AQKV     19456        // [1024]
#define WS_BQKV     20480        // [1024]
#define WS_ASIM     21504        // [24]
#define WS_BSIM     21528        // [24]
#define WS_AOUT     21552        // [1024]
#define WS_BOUT     22576        // [1024]
#define WS_QKV_F    32768        // bf16 region starts here (byte off 131072)
// qkv bf16: [896][1024][56] = 51,380,224 elems = 102,760,448 B. total ws ~98.1 MiB
// xt f32 [512][50176] lives in d_out (exactly out_size floats); dead after k1.

// ---------------- K0: x (B,C,T,H,W) -> xt[c][p], p = ((b*4+t)*56+w)*56+h ----------------
__global__ __launch_bounds__(256) void k0_transpose(const float* __restrict__ x,
                                                    float* __restrict__ xt) {
    int pi = blockIdx.x;                 // (b*512 + c)*4 + t
    int b = pi >> 11, c = (pi >> 2) & 511, t = pi & 3;
    __shared__ float tl[56][57];
    const float* src = x + (size_t)pi * 3136;
    for (int e = threadIdx.x; e < 3136; e += 256) {
        int h = e / 56, w = e - h * 56;
        tl[h][w] = src[e];
    }
    __syncthreads();
    float* dst = xt + (size_t)c * 50176 + (size_t)(b * 4 + t) * 3136;
    for (int e = threadIdx.x; e < 3136; e += 256) {
        int w = e / 56, h = e - w * 56;
        dst[e] = tl[h][w];
    }
}

// ---------------- K1: qkv[n][o][h] = sum_c w[o][c] * xt[c][n*56+h]  (bf16 out) ----------------
__global__ __launch_bounds__(256) void k1_gemm(const float* __restrict__ xt,
                                               const float* __restrict__ w,
                                               bf* __restrict__ qkv) {
    __shared__ float As[16][68];
    __shared__ float Bs[16][68];
    int tid = threadIdx.x;
    int p0 = blockIdx.x * 64;            // 784 tiles
    int o0 = blockIdx.y * 64;            // 16 tiles
    int pp  = tid & 63;
    int kkB = tid >> 6;
    int kkA = tid & 15;
    int ooA = tid >> 4;
    const float* bbase = xt + (size_t)(p0 + pp);
    const float* wbase = w + (size_t)(o0 + ooA) * 512 + kkA;
    int tx = tid & 15, ty = tid >> 4;
    float acc[4][4];
#pragma unroll
    for (int u = 0; u < 4; ++u)
#pragma unroll
        for (int v = 0; v < 4; ++v) acc[u][v] = 0.f;

    for (int k0 = 0; k0 < 512; k0 += 16) {
#pragma unroll
        for (int s = 0; s < 4; ++s)
            As[kkA][ooA + 16 * s] = wbase[k0 + s * 16 * 512];
#pragma unroll
        for (int s = 0; s < 4; ++s)
            Bs[kkB + 4 * s][pp] = bbase[(size_t)(k0 + kkB + 4 * s) * 50176];
        __syncthreads();
#pragma unroll
        for (int kk = 0; kk < 16; ++kk) {
            float4 av = *reinterpret_cast<const float4*>(&As[kk][ty * 4]);
            float4 bv = *reinterpret_cast<const float4*>(&Bs[kk][tx * 4]);
            acc[0][0] += av.x * bv.x; acc[0][1] += av.x * bv.y; acc[0][2] += av.x * bv.z; acc[0][3] += av.x * bv.w;
            acc[1][0] += av.y * bv.x; acc[1][1] += av.y * bv.y; acc[1][2] += av.y * bv.z; acc[1][3] += av.y * bv.w;
            acc[2][0] += av.z * bv.x; acc[2][1] += av.z * bv.y; acc[2][2] += av.z * bv.z; acc[2][3] += av.z * bv.w;
            acc[3][0] += av.w * bv.x; acc[3][1] += av.w * bv.y; acc[3][2] += av.w * bv.z; acc[3][3] += av.w * bv.w;
        }
        __syncthreads();
    }
#pragma unroll
    for (int v = 0; v < 4; ++v) {
        int pq = p0 + tx * 4 + v;
        int nn = pq / 56, hh = pq - nn * 56;
        size_t base = (size_t)nn * 57344 + hh;
#pragma unroll
        for (int u = 0; u < 4; ++u) {
            int o = o0 + ty * 4 + u;
            qkv[base + (size_t)o * 56] = __float2bfloat16(acc[u][v]);
        }
    }
}

// ---------------- K1b: per-o BN coeffs for qkv ----------------
__global__ __launch_bounds__(256) void k1b_stats(const bf* __restrict__ qkv,
                                                 const float* __restrict__ gamma,
                                                 const float* __restrict__ beta,
                                                 float* __restrict__ a_c, float* __restrict__ b_c) {
    int o = blockIdx.x;
    const bf* base = qkv + (size_t)o * 56;
    float s = 0.f, s2 = 0.f;
    for (int e = threadIdx.x; e < 50176; e += 256) {
        int n = e / 56, h = e - n * 56;
        float v = __bfloat162float(base[(size_t)n * 57344 + h]);
        s += v; s2 += v * v;
    }
    __shared__ float rs_[2][4];
    for (int off = 32; off; off >>= 1) { s += __shfl_down(s, off); s2 += __shfl_down(s2, off); }
    int wv = threadIdx.x >> 6, ln = threadIdx.x & 63;
    if (ln == 0) { rs_[0][wv] = s; rs_[1][wv] = s2; }
    __syncthreads();
    if (threadIdx.x == 0) {
        s  = rs_[0][0] + rs_[0][1] + rs_[0][2] + rs_[0][3];
        s2 = rs_[1][0] + rs_[1][1] + rs_[1][2] + rs_[1][3];
        float inv = 1.f / 50176.f;
        float mean = s * inv;
        float var = s2 * inv - mean * mean;
        float a = gamma[o] * rsqrtf(var + EPS);
        a_c[o] = a; b_c[o] = beta[o] - a * mean;
    }
}

// ---------------- K2: sim BN stats (recompute qk/qr/kr) ----------------
__global__ __launch_bounds__(256) void k2_simstats(const bf* __restrict__ qkv,
                                                   const float* __restrict__ rel,
                                                   const float* __restrict__ aq,
                                                   const float* __restrict__ bq,
                                                   float* __restrict__ ssum, float* __restrict__ ssq) {
    int blk = blockIdx.x;
    int n = blk >> 3, g = blk & 7;
    __shared__ float qs[64][57];
    __shared__ float rs[64][111];
    int tid = threadIdx.x;
    const bf* qbase = qkv + (size_t)n * 57344 + (size_t)g * 128 * 56;
    for (int e = tid; e < 64 * 56; e += 256) {
        int c = e / 56, i = e - c * 56;
        int o = g * 128 + c;
        qs[c][i] = aq[o] * __bfloat162float(qbase[c * 56 + i]) + bq[o];
    }
    for (int e = tid; e < 64 * 111; e += 256) {
        int c = e / 111, d = e - c * 111;
        rs[c][d] = rel[c * 111 + d];
    }
    __syncthreads();
    float s0 = 0, s1 = 0, s2_ = 0, q0 = 0, q1 = 0, q2 = 0;
    for (int e = tid; e < 3136; e += 256) {
        int i = e / 56, j = e - i * 56;
        int dq = i - j + 55, dk = j - i + 55;
        float qk = 0, qr = 0, kr = 0;
#pragma unroll
        for (int c = 0; c < 32; ++c) {
            float qv = qs[c][i], kv = qs[32 + c][j];
            qk += qv * kv;
            qr += qv * rs[c][dq];
            kr += kv * rs[32 + c][dk];
        }
        s0 += qk; q0 += qk * qk;
        s1 += qr; q1 += qr * qr;
        s2_ += kr; q2 += kr * kr;
    }
    __shared__ float red[6][4];
    float vals[6] = {s0, s1, s2_, q0, q1, q2};
    int wv = tid >> 6, ln = tid & 63;
#pragma unroll
    for (int v = 0; v < 6; ++v) {
        float xv = vals[v];
        for (int off = 32; off; off >>= 1) xv += __shfl_down(xv, off);
        if (ln == 0) red[v][wv] = xv;
    }
    __syncthreads();
    if (tid < 6) {
        float tot = red[tid][0] + red[tid][1] + red[tid][2] + red[tid][3];
        int comp = (tid < 3) ? tid : tid - 3;
        int ch = comp * 8 + g;
        int bkt = blk & 63;
        float* dst = (tid < 3) ? ssum : ssq;
        atomicAdd(&dst[ch * 64 + bkt], tot);
    }
}

__global__ void k2b_coef(const float* __restrict__ ssum, const float* __restrict__ ssq,
                         const float* __restrict__ gs, const float* __restrict__ bs,
                         float* __restrict__ a_c, float* __restrict__ b_c) {
    int c = threadIdx.x;
    if (c >= 24) return;
    float s = 0, s2 = 0;
    for (int k = 0; k < 64; ++k) { s += ssum[c * 64 + k]; s2 += ssq[c * 64 + k]; }
    float inv = 1.f / 2809856.f;
    float mean = s * inv;
    float var = s2 * inv - mean * mean;
    float a = gs[c] * rsqrtf(var + EPS);
    a_c[c] = a; b_c[c] = bs[c] - a * mean;
}

// ---------------- K3: attention core; writes packed (sv,sve) bf16 pairs into own qkv slice ----------------
__global__ __launch_bounds__(512) void k3_attn(bf* __restrict__ qkv,
                                               const float* __restrict__ rel,
                                               const float* __restrict__ aq, const float* __restrict__ bq,
                                               const float* __restrict__ asim, const float* __restrict__ bsim,
                                               float* __restrict__ osum, float* __restrict__ osq) {
    int blk = blockIdx.x;
    int n = blk >> 3, g = blk & 7;
    __shared__ float qs[64][57];     // phase1: q,k ; phase2: v
    __shared__ float rs[64][111];    // phase1: rel[0:64] ; phase2: rel[64:128]
    __shared__ float sm[56][57];
    __shared__ float red[4][64][8];
    int tid = threadIdx.x;
    bf* qbase = qkv + (size_t)n * 57344 + (size_t)g * 128 * 56;

    for (int e = tid; e < 64 * 56; e += 512) {
        int c = e / 56, i = e - c * 56;
        int o = g * 128 + c;
        qs[c][i] = aq[o] * __bfloat162float(qbase[c * 56 + i]) + bq[o];
    }
    for (int e = tid; e < 64 * 111; e += 512) {
        int c = e / 111, d = e - c * 111;
        rs[c][d] = rel[c * 111 + d];
    }
    __syncthreads();

    float a0 = asim[g], a1 = asim[8 + g], a2 = asim[16 + g];
    float bb = bsim[g] + bsim[8 + g] + bsim[16 + g];
    for (int e = tid; e < 3136; e += 512) {
        int i = e / 56, j = e - i * 56;
        int dq = i - j + 55, dk = j - i + 55;
        float qk = 0, qr = 0, kr = 0;
#pragma unroll
        for (int c = 0; c < 32; ++c) {
            float qv = qs[c][i], kv = qs[32 + c][j];
            qk += qv * kv;
            qr += qv * rs[c][dq];
            kr += kv * rs[32 + c][dk];
        }
        sm[i][j] = a0 * qk + a1 * qr + a2 * kr + bb;
    }
    __syncthreads();

    // phase-2 loads (v rows, rel[64:128]) overlapped with softmax
    for (int e = tid; e < 64 * 56; e += 512) {
        int c = e / 56, i = e - c * 56;
        int o = g * 128 + 64 + c;
        qs[c][i] = aq[o] * __bfloat162float(qbase[(64 + c) * 56 + i]) + bq[o];
    }
    for (int e = tid; e < 64 * 111; e += 512) {
        int c = e / 111, d = e - c * 111;
        rs[c][d] = rel[(64 + c) * 111 + d];
    }
    int wv = tid >> 6, ln = tid & 63;
    for (int i = wv; i < 56; i += 8) {
        float v = (ln < 56) ? sm[i][ln] : -1e30f;
        float m = v;
#pragma unroll
        for (int off = 32; off; off >>= 1) m = fmaxf(m, __shfl_xor(m, off));
        float p = (ln < 56) ? __expf(v - m) : 0.f;
        float su = p;
#pragma unroll
        for (int off = 32; off; off >>= 1) su += __shfl_xor(su, off);
        if (ln < 56) sm[i][ln] = p / su;
    }
    __syncthreads();   // all reads of this block's qkv slice are complete past here

    int c = tid & 63, half = tid >> 6;
    const float* vrow = &qs[c][0];
    const float* rrow = &rs[c][0];
    uint32_t* svz = reinterpret_cast<uint32_t*>(qbase);   // overwrite own slice: [64*56] packed pairs
    float ls0 = 0, ls1 = 0, ls2 = 0, ls3 = 0;
#pragma unroll
    for (int r = 0; r < 7; ++r) {
        int i = half * 7 + r;
        float acc1 = 0.f, acc2 = 0.f;
        const float* rr = rrow + i + 55;
#pragma unroll 8
        for (int j = 0; j < 56; ++j) {
            float wgt = sm[i][j];
            acc1 += wgt * vrow[j];
            acc2 += wgt * rr[-j];
        }
        union { bf h[2]; uint32_t u; } pk;
        pk.h[0] = __float2bfloat16(acc1);
        pk.h[1] = __float2bfloat16(acc2);
        svz[c * 56 + i] = pk.u;
        ls0 += acc1; ls1 += acc1 * acc1; ls2 += acc2; ls3 += acc2 * acc2;
    }
    red[0][c][half] = ls0; red[1][c][half] = ls1; red[2][c][half] = ls2; red[3][c][half] = ls3;
    __syncthreads();
    if (tid < 64) {
        float t0 = 0, t1 = 0, t2 = 0, t3 = 0;
#pragma unroll
        for (int hh = 0; hh < 8; ++hh) {
            t0 += red[0][tid][hh]; t1 += red[1][tid][hh];
            t2 += red[2][tid][hh]; t3 += red[3][tid][hh];
        }
        int o2 = (g * 64 + tid) * 2;
        int bkt = blk & 7;
        atomicAdd(&osum[o2 * 8 + bkt], t0);
        atomicAdd(&osq [o2 * 8 + bkt], t1);
        atomicAdd(&osum[(o2 + 1) * 8 + bkt], t2);
        atomicAdd(&osq [(o2 + 1) * 8 + bkt], t3);
    }
}

__global__ __launch_bounds__(256) void k3b_coef(const float* __restrict__ osum, const float* __restrict__ osq,
                                                const float* __restrict__ go, const float* __restrict__ bo,
                                                float* __restrict__ a_c, float* __restrict__ b_c) {
    int o = blockIdx.x * 256 + threadIdx.x;
    float s = 0, s2 = 0;
#pragma unroll
    for (int k = 0; k < 8; ++k) { s += osum[o * 8 + k]; s2 += osq[o * 8 + k]; }
    float inv = 1.f / 50176.f;
    float mean = s * inv;
    float var = s2 * inv - mean * mean;
    float a = go[o] * rsqrtf(var + EPS);
    a_c[o] = a; b_c[o] = bo[o] - a * mean;
}

// ---------------- K4: out BN + pair-sum + transpose to (B,OUT,T,H,W) ----------------
__global__ __launch_bounds__(256) void k4_out(const uint32_t* __restrict__ svz,
                                              const float* __restrict__ ao, const float* __restrict__ bo,
                                              float* __restrict__ out) {
    int blk = blockIdx.x;              // (bt)*512 + oc
    int oc = blk & 511, bt = blk >> 9;
    int b = bt >> 2, tt = bt & 3;
    int g = oc >> 6, c = oc & 63;
    __shared__ float tile[56][57];
    int tid = threadIdx.x;
    int o_sv = oc * 2, o_sve = oc * 2 + 1;
    float asv = ao[o_sv], bsv = bo[o_sv], asve = ao[o_sve], bsve = bo[o_sve];
    float badd = bsv + bsve;
    int nbase = (b * 4 + tt) * 56;
    for (int e = tid; e < 3136; e += 256) {
        int wq = e / 56, h = e - wq * 56;
        size_t idx = (size_t)(nbase + wq) * 28672 + (size_t)g * 3584 + c * 56 + h;
        union { uint32_t u; bf hh[2]; } pk;
        pk.u = svz[idx];
        tile[wq][h] = asv * __bfloat162float(pk.hh[0]) + asve * __bfloat162float(pk.hh[1]) + badd;
    }
    __syncthreads();
    size_t ob = ((size_t)(b * 512 + oc) * 4 + tt) * 3136;
    for (int e = tid; e < 3136; e += 256) {
        int h = e / 56, wq = e - h * 56;
        out[ob + h * 56 + wq] = tile[wq][h];
    }
}

extern "C" void kernel_launch(void* const* d_in, const int* in_sizes, int n_in,
                              void* d_out, int out_size, void* d_ws, size_t ws_size,
                              hipStream_t stream) {
    (void)in_sizes; (void)n_in; (void)out_size; (void)ws_size;
    const float* x     = (const float*)d_in[0];
    const float* w_qkv = (const float*)d_in[1];
    const float* g_qkv = (const float*)d_in[2];
    const float* b_qkv = (const float*)d_in[3];
    const float* rel   = (const float*)d_in[4];
    const float* g_sim = (const float*)d_in[5];
    const float* b_sim = (const float*)d_in[6];
    const float* g_out = (const float*)d_in[7];
    const float* b_out = (const float*)d_in[8];
    float* ws  = (float*)d_ws;
    float* out = (float*)d_out;
    bf*    qkv = (bf*)(ws + WS_QKV_F);
    float* xt  = out;   // xt[512][50176] hosted in d_out; dead after k1; k4 overwrites d_out

    hipMemsetAsync(ws, 0, WS_ZERO_END * sizeof(float), stream);
    k0_transpose<<<8192, 256, 0, stream>>>(x, xt);
    k1_gemm<<<dim3(784, 16), 256, 0, stream>>>(xt, w_qkv, qkv);
    k1b_stats<<<1024, 256, 0, stream>>>(qkv, g_qkv, b_qkv, ws + WS_AQKV, ws + WS_BQKV);
    k2_simstats<<<7168, 256, 0, stream>>>(qkv, rel, ws + WS_AQKV, ws + WS_BQKV,
                                          ws + WS_SIMSUM, ws + WS_SIMSQ);
    k2b_coef<<<1, 64, 0, stream>>>(ws + WS_SIMSUM, ws + WS_SIMSQ, g_sim, b_sim,
                                   ws + WS_ASIM, ws + WS_BSIM);
    k3_attn<<<7168, 512, 0, stream>>>(qkv, rel, ws + WS_AQKV, ws + WS_BQKV,
                                      ws + WS_ASIM, ws + WS_BSIM,
                                      ws + WS_OUTSUM, ws + WS_OUTSQ);
    k3b_coef<<<4, 256, 0, stream>>>(ws + WS_OUTSUM, ws + WS_OUTSQ, g_out, b_out,
                                    ws + WS_AOUT, ws + WS_BOUT);
    k4_out<<<8192, 256, 0, stream>>>((const uint32_t*)qkv, ws + WS_AOUT, ws + WS_BOUT, out);
}

// Round 3
// 1106.080 us; speedup vs baseline: 1.5932x; 1.5932x over previous
//
#include <hip/hip_runtime.h>
#include <hip/hip_bf16.h>

#define EPS 1e-5f
typedef __hip_bfloat16 bf;
typedef __attribute__((ext_vector_type(8))) short bf16x8;
typedef __attribute__((ext_vector_type(4))) float f32x4;

// Sizes: B=4, C_IN=512, T=4, H=W=K=56, G=8, GP=64, OCH=1024
// NB = 896 ; NP = 50176
#define WS_SIMSUM   0
#define WS_SIMSQ    1536
#define WS_OUTSUM   3072
#define WS_OUTSQ    11264
#define WS_ZERO_END 19456
#define WS_AQKV     19456
#define WS_BQKV     20480
#define WS_ASIM     21504
#define WS_BSIM     21528
#define WS_AOUT     21552
#define WS_BOUT     22576
#define WS_QKV_F    32768
// qkv bf16 [896][1024][56] = 51,380,224 elems, starts at ws+32768 floats. ws total ~98.1 MiB
// d_out scratch: xbt bf16 [50176][512] = 51,380,224 B at offset 0; wb bf16 [1024][512] at byte 51,380,224.

__device__ __forceinline__ void gload_lds16(const void* g, void* l) {
    __builtin_amdgcn_global_load_lds(
        (const __attribute__((address_space(1))) void*)g,
        (__attribute__((address_space(3))) void*)l, 16, 0, 0);
}

// ---------------- K0: x (B,C,T,H,W) f32 -> xbt[p][c] bf16, p = ((b*4+t)*56+w)*56+h ----------------
__global__ __launch_bounds__(256) void k0_transpose(const float* __restrict__ x,
                                                    bf* __restrict__ xbt) {
    int bid = blockIdx.x;                // ((b*4+t)*56 + h)
    int h = bid % 56, bt = bid / 56;
    int b = bt >> 2, t = bt & 3;
    __shared__ short tile[512 * 57];     // tile[c*57 + w]
    const float* src = x + (((size_t)(b * 512) * 4 + t) * 3136) + h * 56;
    for (int e = threadIdx.x; e < 512 * 56; e += 256) {
        int c = e / 56, w = e - c * 56;
        float v = src[(size_t)c * 12544 + w];
        tile[c * 57 + w] = __hip_bfloat16_raw(__float2bfloat16(v)).x;
    }
    __syncthreads();
    short* dst = reinterpret_cast<short*>(xbt);
    size_t pbase = ((size_t)bt * 56) * 56 + h;   // p = pbase + w*56
    for (int e = threadIdx.x; e < 512 * 56; e += 256) {
        int w = e >> 9, c = e & 511;
        dst[(pbase + (size_t)w * 56) * 512 + c] = tile[c * 57 + w];
    }
}

// ---------------- KW: w f32 [1024][512] -> bf16 ----------------
__global__ __launch_bounds__(256) void kw_conv(const float* __restrict__ w, bf* __restrict__ wb) {
    int i = (blockIdx.x * 256 + threadIdx.x) * 4;
#pragma unroll
    for (int u = 0; u < 4; ++u) wb[i + u] = __float2bfloat16(w[i + u]);
}

// ---------------- K1: MFMA GEMM qkv[n][o][h] = sum_c wb[o][c] * xbt[p][c], p=n*56+h ----------------
__global__ __launch_bounds__(256) void k1_mfma(const bf* __restrict__ xbt,
                                               const bf* __restrict__ wb,
                                               bf* __restrict__ qkv) {
    __shared__ short As[128 * 64];   // [o][c] 16KB
    __shared__ short Bs[112 * 64];   // [p][c] 14KB
    int tid = threadIdx.x;
    int p0 = blockIdx.x * 112;       // 448
    int o0 = blockIdx.y * 128;       // 8
    const short* aG = reinterpret_cast<const short*>(wb);
    const short* bG = reinterpret_cast<const short*>(xbt);
    int wv = tid >> 6, l = tid & 63, r16 = l & 15, q4 = l >> 4;

    f32x4 acc[2][7];
#pragma unroll
    for (int i = 0; i < 2; ++i)
#pragma unroll
        for (int j = 0; j < 7; ++j) acc[i][j] = (f32x4){0.f, 0.f, 0.f, 0.f};

    const short* aBase = &As[(wv * 32 + r16) * 64 + q4 * 8];
    const short* bBase = &Bs[r16 * 64 + q4 * 8];

    for (int k0 = 0; k0 < 512; k0 += 64) {
        // stage A: 1024 x 16B chunks
        int ch = tid;
#pragma unroll
        for (int it = 0; it < 4; ++it, ch += 256) {
            int row = ch >> 3, c8 = (ch & 7) << 3;
            gload_lds16(aG + (((size_t)(o0 + row)) << 9) + k0 + c8, &As[ch << 3]);
        }
        // stage B: 896 x 16B chunks
        ch = tid;
#pragma unroll
        for (int it = 0; it < 3; ++it, ch += 256) {
            int row = ch >> 3, c8 = (ch & 7) << 3;
            gload_lds16(bG + (((size_t)(p0 + row)) << 9) + k0 + c8, &Bs[ch << 3]);
        }
        if (tid < 128) {
            int row = (tid + 768) >> 3, c8 = (tid & 7) << 3;
            gload_lds16(bG + (((size_t)(p0 + row)) << 9) + k0 + c8, &Bs[(tid + 768) << 3]);
        }
        __syncthreads();
#pragma unroll
        for (int kk = 0; kk < 2; ++kk) {
            bf16x8 a0 = *reinterpret_cast<const bf16x8*>(aBase + kk * 32);
            bf16x8 a1 = *reinterpret_cast<const bf16x8*>(aBase + 16 * 64 + kk * 32);
#pragma unroll
            for (int j = 0; j < 7; ++j) {
                bf16x8 bj = *reinterpret_cast<const bf16x8*>(bBase + j * 16 * 64 + kk * 32);
                acc[0][j] = __builtin_amdgcn_mfma_f32_16x16x32_bf16(a0, bj, acc[0][j], 0, 0, 0);
                acc[1][j] = __builtin_amdgcn_mfma_f32_16x16x32_bf16(a1, bj, acc[1][j], 0, 0, 0);
            }
        }
        __syncthreads();
    }
#pragma unroll
    for (int j = 0; j < 7; ++j) {
        int p = p0 + j * 16 + r16;
        int n = p / 56, h = p - n * 56;
        size_t nb = (size_t)n * 57344 + h;
#pragma unroll
        for (int i = 0; i < 2; ++i) {
            int ob = o0 + wv * 32 + i * 16 + q4 * 4;
#pragma unroll
            for (int r = 0; r < 4; ++r)
                qkv[nb + (size_t)(ob + r) * 56] = __float2bfloat16(acc[i][j][r]);
        }
    }
}

// ---------------- K1b: per-o BN coeffs for qkv ----------------
__global__ __launch_bounds__(256) void k1b_stats(const bf* __restrict__ qkv,
                                                 const float* __restrict__ gamma,
                                                 const float* __restrict__ beta,
                                                 float* __restrict__ a_c, float* __restrict__ b_c) {
    int o = blockIdx.x;
    const bf* base = qkv + (size_t)o * 56;
    float s = 0.f, s2 = 0.f;
    for (int e = threadIdx.x; e < 50176; e += 256) {
        int n = e / 56, h = e - n * 56;
        float v = __bfloat162float(base[(size_t)n * 57344 + h]);
        s += v; s2 += v * v;
    }
    __shared__ float rs_[2][4];
    for (int off = 32; off; off >>= 1) { s += __shfl_down(s, off); s2 += __shfl_down(s2, off); }
    int wv = threadIdx.x >> 6, ln = threadIdx.x & 63;
    if (ln == 0) { rs_[0][wv] = s; rs_[1][wv] = s2; }
    __syncthreads();
    if (threadIdx.x == 0) {
        s  = rs_[0][0] + rs_[0][1] + rs_[0][2] + rs_[0][3];
        s2 = rs_[1][0] + rs_[1][1] + rs_[1][2] + rs_[1][3];
        float inv = 1.f / 50176.f;
        float mean = s * inv;
        float var = s2 * inv - mean * mean;
        float a = gamma[o] * rsqrtf(var + EPS);
        a_c[o] = a; b_c[o] = beta[o] - a * mean;
    }
}

// ---------------- K2: sim BN stats (recompute qk/qr/kr) ----------------
__global__ __launch_bounds__(256) void k2_simstats(const bf* __restrict__ qkv,
                                                   const float* __restrict__ rel,
                                                   const float* __restrict__ aq,
                                                   const float* __restrict__ bq,
                                                   float* __restrict__ ssum, float* __restrict__ ssq) {
    int blk = blockIdx.x;
    int n = blk >> 3, g = blk & 7;
    __shared__ float qs[64][57];
    __shared__ float rs[64][111];
    int tid = threadIdx.x;
    const bf* qbase = qkv + (size_t)n * 57344 + (size_t)g * 128 * 56;
    for (int e = tid; e < 64 * 56; e += 256) {
        int c = e / 56, i = e - c * 56;
        int o = g * 128 + c;
        qs[c][i] = aq[o] * __bfloat162float(qbase[c * 56 + i]) + bq[o];
    }
    for (int e = tid; e < 64 * 111; e += 256) {
        int c = e / 111, d = e - c * 111;
        rs[c][d] = rel[c * 111 + d];
    }
    __syncthreads();
    float s0 = 0, s1 = 0, s2_ = 0, q0 = 0, q1 = 0, q2 = 0;
    for (int e = tid; e < 3136; e += 256) {
        int i = e / 56, j = e - i * 56;
        int dq = i - j + 55, dk = j - i + 55;
        float qk = 0, qr = 0, kr = 0;
#pragma unroll
        for (int c = 0; c < 32; ++c) {
            float qv = qs[c][i], kv = qs[32 + c][j];
            qk += qv * kv;
            qr += qv * rs[c][dq];
            kr += kv * rs[32 + c][dk];
        }
        s0 += qk; q0 += qk * qk;
        s1 += qr; q1 += qr * qr;
        s2_ += kr; q2 += kr * kr;
    }
    __shared__ float red[6][4];
    float vals[6] = {s0, s1, s2_, q0, q1, q2};
    int wv = tid >> 6, ln = tid & 63;
#pragma unroll
    for (int v = 0; v < 6; ++v) {
        float xv = vals[v];
        for (int off = 32; off; off >>= 1) xv += __shfl_down(xv, off);
        if (ln == 0) red[v][wv] = xv;
    }
    __syncthreads();
    if (tid < 6) {
        float tot = red[tid][0] + red[tid][1] + red[tid][2] + red[tid][3];
        int comp = (tid < 3) ? tid : tid - 3;
        int ch = comp * 8 + g;
        int bkt = blk & 63;
        float* dst = (tid < 3) ? ssum : ssq;
        atomicAdd(&dst[ch * 64 + bkt], tot);
    }
}

__global__ void k2b_coef(const float* __restrict__ ssum, const float* __restrict__ ssq,
                         const float* __restrict__ gs, const float* __restrict__ bs,
                         float* __restrict__ a_c, float* __restrict__ b_c) {
    int c = threadIdx.x;
    if (c >= 24) return;
    float s = 0, s2 = 0;
    for (int k = 0; k < 64; ++k) { s += ssum[c * 64 + k]; s2 += ssq[c * 64 + k]; }
    float inv = 1.f / 2809856.f;
    float mean = s * inv;
    float var = s2 * inv - mean * mean;
    float a = gs[c] * rsqrtf(var + EPS);
    a_c[c] = a; b_c[c] = bs[c] - a * mean;
}

// ---------------- K3: attention core; writes packed (sv,sve) bf16 pairs into own qkv slice ----------------
__global__ __launch_bounds__(512) void k3_attn(bf* __restrict__ qkv,
                                               const float* __restrict__ rel,
                                               const float* __restrict__ aq, const float* __restrict__ bq,
                                               const float* __restrict__ asim, const float* __restrict__ bsim,
                                               float* __restrict__ osum, float* __restrict__ osq) {
    int blk = blockIdx.x;
    int n = blk >> 3, g = blk & 7;
    __shared__ float qs[64][57];
    __shared__ float rs[64][111];
    __shared__ float sm[56][57];
    __shared__ float red[4][64][8];
    int tid = threadIdx.x;
    bf* qbase = qkv + (size_t)n * 57344 + (size_t)g * 128 * 56;

    for (int e = tid; e < 64 * 56; e += 512) {
        int c = e / 56, i = e - c * 56;
        int o = g * 128 + c;
        qs[c][i] = aq[o] * __bfloat162float(qbase[c * 56 + i]) + bq[o];
    }
    for (int e = tid; e < 64 * 111; e += 512) {
        int c = e / 111, d = e - c * 111;
        rs[c][d] = rel[c * 111 + d];
    }
    __syncthreads();

    float a0 = asim[g], a1 = asim[8 + g], a2 = asim[16 + g];
    float bb = bsim[g] + bsim[8 + g] + bsim[16 + g];
    for (int e = tid; e < 3136; e += 512) {
        int i = e / 56, j = e - i * 56;
        int dq = i - j + 55, dk = j - i + 55;
        float qk = 0, qr = 0, kr = 0;
#pragma unroll
        for (int c = 0; c < 32; ++c) {
            float qv = qs[c][i], kv = qs[32 + c][j];
            qk += qv * kv;
            qr += qv * rs[c][dq];
            kr += kv * rs[32 + c][dk];
        }
        sm[i][j] = a0 * qk + a1 * qr + a2 * kr + bb;
    }
    __syncthreads();

    for (int e = tid; e < 64 * 56; e += 512) {
        int c = e / 56, i = e - c * 56;
        int o = g * 128 + 64 + c;
        qs[c][i] = aq[o] * __bfloat162float(qbase[(64 + c) * 56 + i]) + bq[o];
    }
    for (int e = tid; e < 64 * 111; e += 512) {
        int c = e / 111, d = e - c * 111;
        rs[c][d] = rel[(64 + c) * 111 + d];
    }
    int wv = tid >> 6, ln = tid & 63;
    for (int i = wv; i < 56; i += 8) {
        float v = (ln < 56) ? sm[i][ln] : -1e30f;
        float m = v;
#pragma unroll
        for (int off = 32; off; off >>= 1) m = fmaxf(m, __shfl_xor(m, off));
        float p = (ln < 56) ? __expf(v - m) : 0.f;
        float su = p;
#pragma unroll
        for (int off = 32; off; off >>= 1) su += __shfl_xor(su, off);
        if (ln < 56) sm[i][ln] = p / su;
    }
    __syncthreads();

    int c = tid & 63, half = tid >> 6;
    const float* vrow = &qs[c][0];
    const float* rrow = &rs[c][0];
    uint32_t* svz = reinterpret_cast<uint32_t*>(qbase);
    float ls0 = 0, ls1 = 0, ls2 = 0, ls3 = 0;
#pragma unroll
    for (int r = 0; r < 7; ++r) {
        int i = half * 7 + r;
        float acc1 = 0.f, acc2 = 0.f;
        const float* rr = rrow + i + 55;
#pragma unroll 8
        for (int j = 0; j < 56; ++j) {
            float wgt = sm[i][j];
            acc1 += wgt * vrow[j];
            acc2 += wgt * rr[-j];
        }
        union { bf h[2]; uint32_t u; } pk;
        pk.h[0] = __float2bfloat16(acc1);
        pk.h[1] = __float2bfloat16(acc2);
        svz[c * 56 + i] = pk.u;
        ls0 += acc1; ls1 += acc1 * acc1; ls2 += acc2; ls3 += acc2 * acc2;
    }
    red[0][c][half] = ls0; red[1][c][half] = ls1; red[2][c][half] = ls2; red[3][c][half] = ls3;
    __syncthreads();
    if (tid < 64) {
        float t0 = 0, t1 = 0, t2 = 0, t3 = 0;
#pragma unroll
        for (int hh = 0; hh < 8; ++hh) {
            t0 += red[0][tid][hh]; t1 += red[1][tid][hh];
            t2 += red[2][tid][hh]; t3 += red[3][tid][hh];
        }
        int o2 = (g * 64 + tid) * 2;
        int bkt = blk & 7;
        atomicAdd(&osum[o2 * 8 + bkt], t0);
        atomicAdd(&osq [o2 * 8 + bkt], t1);
        atomicAdd(&osum[(o2 + 1) * 8 + bkt], t2);
        atomicAdd(&osq [(o2 + 1) * 8 + bkt], t3);
    }
}

__global__ __launch_bounds__(256) void k3b_coef(const float* __restrict__ osum, const float* __restrict__ osq,
                                                const float* __restrict__ go, const float* __restrict__ bo,
                                                float* __restrict__ a_c, float* __restrict__ b_c) {
    int o = blockIdx.x * 256 + threadIdx.x;
    float s = 0, s2 = 0;
#pragma unroll
    for (int k = 0; k < 8; ++k) { s += osum[o * 8 + k]; s2 += osq[o * 8 + k]; }
    float inv = 1.f / 50176.f;
    float mean = s * inv;
    float var = s2 * inv - mean * mean;
    float a = go[o] * rsqrtf(var + EPS);
    a_c[o] = a; b_c[o] = bo[o] - a * mean;
}

// ---------------- K4: out BN + pair-sum + transpose to (B,OUT,T,H,W) ----------------
__global__ __launch_bounds__(256) void k4_out(const uint32_t* __restrict__ svz,
                                              const float* __restrict__ ao, const float* __restrict__ bo,
                                              float* __restrict__ out) {
    int blk = blockIdx.x;
    int oc = blk & 511, bt = blk >> 9;
    int b = bt >> 2, tt = bt & 3;
    int g = oc >> 6, c = oc & 63;
    __shared__ float tile[56][57];
    int tid = threadIdx.x;
    int o_sv = oc * 2, o_sve = oc * 2 + 1;
    float asv = ao[o_sv], bsv = bo[o_sv], asve = ao[o_sve], bsve = bo[o_sve];
    float badd = bsv + bsve;
    int nbase = (b * 4 + tt) * 56;
    for (int e = tid; e < 3136; e += 256) {
        int wq = e / 56, h = e - wq * 56;
        size_t idx = (size_t)(nbase + wq) * 28672 + (size_t)g * 3584 + c * 56 + h;
        union { uint32_t u; bf hh[2]; } pk;
        pk.u = svz[idx];
        tile[wq][h] = asv * __bfloat162float(pk.hh[0]) + asve * __bfloat162float(pk.hh[1]) + badd;
    }
    __syncthreads();
    size_t ob = ((size_t)(b * 512 + oc) * 4 + tt) * 3136;
    for (int e = tid; e < 3136; e += 256) {
        int h = e / 56, wq = e - h * 56;
        out[ob + h * 56 + wq] = tile[wq][h];
    }
}

extern "C" void kernel_launch(void* const* d_in, const int* in_sizes, int n_in,
                              void* d_out, int out_size, void* d_ws, size_t ws_size,
                              hipStream_t stream) {
    (void)in_sizes; (void)n_in; (void)out_size; (void)ws_size;
    const float* x     = (const float*)d_in[0];
    const float* w_qkv = (const float*)d_in[1];
    const float* g_qkv = (const float*)d_in[2];
    const float* b_qkv = (const float*)d_in[3];
    const float* rel   = (const float*)d_in[4];
    const float* g_sim = (const float*)d_in[5];
    const float* b_sim = (const float*)d_in[6];
    const float* g_out = (const float*)d_in[7];
    const float* b_out = (const float*)d_in[8];
    float* ws  = (float*)d_ws;
    float* out = (float*)d_out;
    bf*    qkv = (bf*)(ws + WS_QKV_F);
    bf*    xbt = (bf*)d_out;                                    // [50176][512] bf16, dead after k1
    bf*    wb  = (bf*)((char*)d_out + 51380224);                // [1024][512] bf16

    hipMemsetAsync(ws, 0, WS_ZERO_END * sizeof(float), stream);
    k0_transpose<<<896, 256, 0, stream>>>(x, xbt);
    kw_conv<<<512, 256, 0, stream>>>(w_qkv, wb);
    k1_mfma<<<dim3(448, 8), 256, 0, stream>>>(xbt, wb, qkv);
    k1b_stats<<<1024, 256, 0, stream>>>(qkv, g_qkv, b_qkv, ws + WS_AQKV, ws + WS_BQKV);
    k2_simstats<<<7168, 256, 0, stream>>>(qkv, rel, ws + WS_AQKV, ws + WS_BQKV,
                                          ws + WS_SIMSUM, ws + WS_SIMSQ);
    k2b_coef<<<1, 64, 0, stream>>>(ws + WS_SIMSUM, ws + WS_SIMSQ, g_sim, b_sim,
                                   ws + WS_ASIM, ws + WS_BSIM);
    k3_attn<<<7168, 512, 0, stream>>>(qkv, rel, ws + WS_AQKV, ws + WS_BQKV,
                                      ws + WS_ASIM, ws + WS_BSIM,
                                      ws + WS_OUTSUM, ws + WS_OUTSQ);
    k3b_coef<<<4, 256, 0, stream>>>(ws + WS_OUTSUM, ws + WS_OUTSQ, g_out, b_out,
                                    ws + WS_AOUT, ws + WS_BOUT);
    k4_out<<<8192, 256, 0, stream>>>((const uint32_t*)qkv, ws + WS_AOUT, ws + WS_BOUT, out);
}

// Round 4
// 581.946 us; speedup vs baseline: 3.0281x; 1.9007x over previous
//
#include <hip/hip_runtime.h>
#include <hip/hip_bf16.h>

#define EPS 1e-5f
typedef __hip_bfloat16 bf;
typedef __attribute__((ext_vector_type(8))) short bf16x8;
typedef __attribute__((ext_vector_type(4))) float f32x4;

#define MFMA16(a, b, c) __builtin_amdgcn_mfma_f32_16x16x32_bf16(a, b, c, 0, 0, 0)

// Sizes: B=4, C_IN=512, T=4, H=W=K=56, G=8, GP=64, OCH=1024
// NB = 896 ; NP = 50176
#define WS_SIMSUM   0
#define WS_SIMSQ    1536
#define WS_OUTSUM   3072
#define WS_OUTSQ    11264
#define WS_ZERO_END 19456
#define WS_AQKV     19456
#define WS_BQKV     20480
#define WS_ASIM     21504
#define WS_BSIM     21528
#define WS_AOUT     21552
#define WS_BOUT     22576
// byte offsets for bf16 rel tables (after 23600 floats = 94400 B)
#define RELTQ_B     94400      // [112][32] bf16 = 7168 B
#define RELTK_B     101568     // [112][32] bf16 = 7168 B
#define RELBV_B     108736     // [64][128] bf16 = 16384 B
#define WS_QKV_F    32768      // qkv bf16 [896][1024][56] at byte 131072

__device__ __forceinline__ void gload_lds16(const void* g, void* l) {
    __builtin_amdgcn_global_load_lds(
        (const __attribute__((address_space(1))) void*)g,
        (__attribute__((address_space(3))) void*)l, 16, 0, 0);
}
__device__ __forceinline__ float bfbits2f(short b) {
    return __uint_as_float(((uint32_t)(unsigned short)b) << 16);
}
__device__ __forceinline__ short f2bfbits(float f) {
    return (short)__hip_bfloat16_raw(__float2bfloat16(f)).x;
}

// ---------------- K0: x (B,C,T,H,W) f32 -> xbt[p][c] bf16, p = ((b*4+t)*56+w)*56+h ----------------
__global__ __launch_bounds__(256) void k0_transpose(const float* __restrict__ x,
                                                    bf* __restrict__ xbt) {
    int bid = blockIdx.x;                // ((b*4+t)*56 + h)
    int h = bid % 56, bt = bid / 56;
    int b = bt >> 2, t = bt & 3;
    __shared__ short tile[512 * 57];     // tile[c*57 + w]
    const float* src = x + (((size_t)(b * 512) * 4 + t) * 3136) + h * 56;
    for (int e = threadIdx.x; e < 512 * 56; e += 256) {
        int c = e / 56, w = e - c * 56;
        float v = src[(size_t)c * 12544 + w];
        tile[c * 57 + w] = f2bfbits(v);
    }
    __syncthreads();
    short* dst = reinterpret_cast<short*>(xbt);
    size_t pbase = ((size_t)bt * 56) * 56 + h;   // p = pbase + w*56
    for (int e = threadIdx.x; e < 512 * 56; e += 256) {
        int w = e >> 9, c = e & 511;
        dst[(pbase + (size_t)w * 56) * 512 + c] = tile[c * 57 + w];
    }
}

// ---------------- KW: w f32 [1024][512] -> bf16 ----------------
__global__ __launch_bounds__(256) void kw_conv(const float* __restrict__ w, bf* __restrict__ wb) {
    int i = (blockIdx.x * 256 + threadIdx.x) * 4;
#pragma unroll
    for (int u = 0; u < 4; ++u) wb[i + u] = __float2bfloat16(w[i + u]);
}

// ---------------- KPREP: rel f32 [128][111] -> relTq/relTk [112][32], relBv [64][128] bf16 ----------------
__global__ __launch_bounds__(256) void kprep(const float* __restrict__ rel,
                                             short* __restrict__ relTq,
                                             short* __restrict__ relTk,
                                             short* __restrict__ relBv) {
    int tid = blockIdx.x * 256 + threadIdx.x;
    if (tid < 3584) {
        int d = tid >> 5, c = tid & 31;
        relTq[tid] = f2bfbits(d < 111 ? rel[c * 111 + d] : 0.f);
        relTk[tid] = f2bfbits(d < 111 ? rel[(32 + c) * 111 + d] : 0.f);
    } else if (tid < 11776) {
        int u = tid - 3584, c = u >> 7, d = u & 127;
        relBv[u] = f2bfbits(d < 111 ? rel[(64 + c) * 111 + d] : 0.f);
    }
}

// ---------------- K1: MFMA GEMM qkv[n][o][h] = sum_c wb[o][c] * xbt[p][c], p=n*56+h ----------------
__global__ __launch_bounds__(256) void k1_mfma(const bf* __restrict__ xbt,
                                               const bf* __restrict__ wb,
                                               bf* __restrict__ qkv) {
    __shared__ short As[128 * 64];
    __shared__ short Bs[112 * 64];
    int tid = threadIdx.x;
    int p0 = blockIdx.x * 112;
    int o0 = blockIdx.y * 128;
    const short* aG = reinterpret_cast<const short*>(wb);
    const short* bG = reinterpret_cast<const short*>(xbt);
    int wv = tid >> 6, l = tid & 63, r16 = l & 15, q4 = l >> 4;

    f32x4 acc[2][7];
#pragma unroll
    for (int i = 0; i < 2; ++i)
#pragma unroll
        for (int j = 0; j < 7; ++j) acc[i][j] = (f32x4){0.f, 0.f, 0.f, 0.f};

    const short* aBase = &As[(wv * 32 + r16) * 64 + q4 * 8];
    const short* bBase = &Bs[r16 * 64 + q4 * 8];

    for (int k0 = 0; k0 < 512; k0 += 64) {
        int ch = tid;
#pragma unroll
        for (int it = 0; it < 4; ++it, ch += 256) {
            int row = ch >> 3, c8 = (ch & 7) << 3;
            gload_lds16(aG + (((size_t)(o0 + row)) << 9) + k0 + c8, &As[ch << 3]);
        }
        ch = tid;
#pragma unroll
        for (int it = 0; it < 3; ++it, ch += 256) {
            int row = ch >> 3, c8 = (ch & 7) << 3;
            gload_lds16(bG + (((size_t)(p0 + row)) << 9) + k0 + c8, &Bs[ch << 3]);
        }
        if (tid < 128) {
            int row = (tid + 768) >> 3, c8 = (tid & 7) << 3;
            gload_lds16(bG + (((size_t)(p0 + row)) << 9) + k0 + c8, &Bs[(tid + 768) << 3]);
        }
        __syncthreads();
#pragma unroll
        for (int kk = 0; kk < 2; ++kk) {
            bf16x8 a0 = *reinterpret_cast<const bf16x8*>(aBase + kk * 32);
            bf16x8 a1 = *reinterpret_cast<const bf16x8*>(aBase + 16 * 64 + kk * 32);
#pragma unroll
            for (int j = 0; j < 7; ++j) {
                bf16x8 bj = *reinterpret_cast<const bf16x8*>(bBase + j * 16 * 64 + kk * 32);
                acc[0][j] = MFMA16(a0, bj, acc[0][j]);
                acc[1][j] = MFMA16(a1, bj, acc[1][j]);
            }
        }
        __syncthreads();
    }
#pragma unroll
    for (int j = 0; j < 7; ++j) {
        int p = p0 + j * 16 + r16;
        int n = p / 56, h = p - n * 56;
        size_t nb = (size_t)n * 57344 + h;
#pragma unroll
        for (int i = 0; i < 2; ++i) {
            int ob = o0 + wv * 32 + i * 16 + q4 * 4;
#pragma unroll
            for (int r = 0; r < 4; ++r)
                qkv[nb + (size_t)(ob + r) * 56] = __float2bfloat16(acc[i][j][r]);
        }
    }
}

// ---------------- K1b: per-o BN coeffs for qkv ----------------
__global__ __launch_bounds__(256) void k1b_stats(const bf* __restrict__ qkv,
                                                 const float* __restrict__ gamma,
                                                 const float* __restrict__ beta,
                                                 float* __restrict__ a_c, float* __restrict__ b_c) {
    int o = blockIdx.x;
    const bf* base = qkv + (size_t)o * 56;
    float s = 0.f, s2 = 0.f;
    for (int e = threadIdx.x; e < 50176; e += 256) {
        int n = e / 56, h = e - n * 56;
        float v = __bfloat162float(base[(size_t)n * 57344 + h]);
        s += v; s2 += v * v;
    }
    __shared__ float rs_[2][4];
    for (int off = 32; off; off >>= 1) { s += __shfl_down(s, off); s2 += __shfl_down(s2, off); }
    int wv = threadIdx.x >> 6, ln = threadIdx.x & 63;
    if (ln == 0) { rs_[0][wv] = s; rs_[1][wv] = s2; }
    __syncthreads();
    if (threadIdx.x == 0) {
        s  = rs_[0][0] + rs_[0][1] + rs_[0][2] + rs_[0][3];
        s2 = rs_[1][0] + rs_[1][1] + rs_[1][2] + rs_[1][3];
        float inv = 1.f / 50176.f;
        float mean = s * inv;
        float var = s2 * inv - mean * mean;
        float a = gamma[o] * rsqrtf(var + EPS);
        a_c[o] = a; b_c[o] = beta[o] - a * mean;
    }
}

// ============ shared attention-core helpers (512 threads, 8 waves) ============
// LDS layout (75232 B):
//   qT [64][40] short @0      (5120)   -- q^T [i][c], BN-applied bf16
//   kT [64][40] short @5120   (5120)
//   qkl[56][57] f32   @10240  (12768)  -- qk scores, then p (softmax)
//   Sql[56][112] f32  @23008  (25088)  -- phase2: simB [64][64] bf16 (8192)
//   Krl[56][112] f32  @48096  (25088)  -- phase2: Pb [64][128] bf16 (16384)
//   red           @73184  (2048)
// phase2: vB [64][64] bf16 @0 (8192, over qT/kT)

__device__ __forceinline__ void stage_qk(const bf* __restrict__ qbase,
                                         const float* __restrict__ aq, const float* __restrict__ bq,
                                         int g, short* qT, short* kT, int tid) {
    for (int u = tid; u < 448; u += 512) {
        int c = u / 7, ch = u - c * 7;      // c 0..63, ch 0..6 (i-chunk of 8)
        int o = g * 128 + c;
        float a = aq[o], b = bq[o];
        bf16x8 raw = *reinterpret_cast<const bf16x8*>(qbase + c * 56 + ch * 8);
        short* dst = (c < 32) ? qT : kT;
        int cc = c & 31, ibase = ch * 8;
#pragma unroll
        for (int u8 = 0; u8 < 8; ++u8)
            dst[(ibase + u8) * 40 + cc] = f2bfbits(a * bfbits2f(raw[u8]) + b);
    }
}

__device__ __forceinline__ void phase1(const short* qT, const short* kT,
                                       const short* __restrict__ relTq,
                                       const short* __restrict__ relTk,
                                       float* qkl, float* Sql, float* Krl, int tid) {
    int w = tid >> 6, l = tid & 63;
    int m = w >> 1, s = w & 1;
    int la = l & 15, lb = l >> 4;
    bf16x8 aqf = *reinterpret_cast<const bf16x8*>(&qT[(m * 16 + la) * 40 + lb * 8]);
    bf16x8 akf = *reinterpret_cast<const bf16x8*>(&kT[(m * 16 + la) * 40 + lb * 8]);
    // qk[i][j]
#pragma unroll
    for (int t = 0; t < 2; ++t) {
        int nt = 2 * s + t;
        bf16x8 bk = *reinterpret_cast<const bf16x8*>(&kT[(nt * 16 + la) * 40 + lb * 8]);
        f32x4 acc = {0.f, 0.f, 0.f, 0.f};
        acc = MFMA16(aqf, bk, acc);
        int j = nt * 16 + la;
        if (j < 56) {
#pragma unroll
            for (int r = 0; r < 4; ++r) {
                int i = m * 16 + lb * 4 + r;
                if (i < 56) qkl[i * 57 + j] = acc[r];
            }
        }
    }
    int ndt = s ? 3 : 4, dt0 = s * 4;
    // Sq[i][d] = sum_c q[c,i] rel_q[c,d]
    for (int t = 0; t < ndt; ++t) {
        int dt = dt0 + t;
        bf16x8 br = *reinterpret_cast<const bf16x8*>(&relTq[(dt * 16 + la) * 32 + lb * 8]);
        f32x4 acc = {0.f, 0.f, 0.f, 0.f};
        acc = MFMA16(aqf, br, acc);
        int d = dt * 16 + la;
#pragma unroll
        for (int r = 0; r < 4; ++r) {
            int i = m * 16 + lb * 4 + r;
            if (i < 56) Sql[i * 112 + d] = acc[r];
        }
    }
    // Kr[j][d] = sum_c k[c,j] rel_k[c,d]
    for (int t = 0; t < ndt; ++t) {
        int dt = dt0 + t;
        bf16x8 br = *reinterpret_cast<const bf16x8*>(&relTk[(dt * 16 + la) * 32 + lb * 8]);
        f32x4 acc = {0.f, 0.f, 0.f, 0.f};
        acc = MFMA16(akf, br, acc);
        int d = dt * 16 + la;
#pragma unroll
        for (int r = 0; r < 4; ++r) {
            int j = m * 16 + lb * 4 + r;
            if (j < 56) Krl[j * 112 + d] = acc[r];
        }
    }
}

// ---------------- K2: sim BN stats via MFMA ----------------
__global__ __launch_bounds__(512) void k2_mfma(const bf* __restrict__ qkv,
                                               const short* __restrict__ relTq,
                                               const short* __restrict__ relTk,
                                               const float* __restrict__ aq, const float* __restrict__ bq,
                                               float* __restrict__ ssum, float* __restrict__ ssq) {
    __shared__ __align__(16) char smem[75232];
    short* qT  = (short*)smem;
    short* kT  = (short*)(smem + 5120);
    float* qkl = (float*)(smem + 10240);
    float* Sql = (float*)(smem + 23008);
    float* Krl = (float*)(smem + 48096);
    float* red = (float*)(smem + 73184);
    int blk = blockIdx.x, n = blk >> 3, g = blk & 7, tid = threadIdx.x;
    const bf* qbase = qkv + (size_t)n * 57344 + (size_t)g * 7168;
    stage_qk(qbase, aq, bq, g, qT, kT, tid);
    __syncthreads();
    phase1(qT, kT, relTq, relTk, qkl, Sql, Krl, tid);
    __syncthreads();
    float s0 = 0, s1 = 0, s2 = 0, q0 = 0, q1 = 0, q2 = 0;
    for (int e = tid; e < 3136; e += 512) {
        int i = e / 56, j = e - i * 56;
        float a = qkl[i * 57 + j];
        float b = Sql[i * 112 + (i - j + 55)];
        float c = Krl[j * 112 + (j - i + 55)];
        s0 += a; q0 += a * a; s1 += b; q1 += b * b; s2 += c; q2 += c * c;
    }
    int w = tid >> 6, l = tid & 63;
    float vals[6] = {s0, s1, s2, q0, q1, q2};
#pragma unroll
    for (int v = 0; v < 6; ++v) {
        for (int off = 32; off; off >>= 1) vals[v] += __shfl_down(vals[v], off);
        if (l == 0) red[v * 8 + w] = vals[v];
    }
    __syncthreads();
    if (tid < 6) {
        float tot = 0;
#pragma unroll
        for (int k = 0; k < 8; ++k) tot += red[tid * 8 + k];
        int comp = (tid < 3) ? tid : tid - 3;
        int ch = comp * 8 + g;
        int bkt = blk & 63;
        atomicAdd((tid < 3 ? ssum : ssq) + ch * 64 + bkt, tot);
    }
}

__global__ void k2b_coef(const float* __restrict__ ssum, const float* __restrict__ ssq,
                         const float* __restrict__ gs, const float* __restrict__ bs,
                         float* __restrict__ a_c, float* __restrict__ b_c) {
    int c = threadIdx.x;
    if (c >= 24) return;
    float s = 0, s2 = 0;
    for (int k = 0; k < 64; ++k) { s += ssum[c * 64 + k]; s2 += ssq[c * 64 + k]; }
    float inv = 1.f / 2809856.f;
    float mean = s * inv;
    float var = s2 * inv - mean * mean;
    float a = gs[c] * rsqrtf(var + EPS);
    a_c[c] = a; b_c[c] = bs[c] - a * mean;
}

// ---------------- K3: full attention core via MFMA ----------------
__global__ __launch_bounds__(512) void k3_mfma(bf* __restrict__ qkv,
                                               const short* __restrict__ relTq,
                                               const short* __restrict__ relTk,
                                               const short* __restrict__ relBv,
                                               const float* __restrict__ aq, const float* __restrict__ bq,
                                               const float* __restrict__ asim, const float* __restrict__ bsim,
                                               float* __restrict__ osum, float* __restrict__ osq) {
    __shared__ __align__(16) char smem[75232];
    short* qT   = (short*)smem;
    short* kT   = (short*)(smem + 5120);
    float* qkl  = (float*)(smem + 10240);
    float* Sql  = (float*)(smem + 23008);
    float* Krl  = (float*)(smem + 48096);
    float* red  = (float*)(smem + 73184);
    short* vB   = (short*)smem;            // phase2 overlays
    short* simB = (short*)(smem + 23008);
    short* Pb   = (short*)(smem + 48096);

    int blk = blockIdx.x, n = blk >> 3, g = blk & 7, tid = threadIdx.x;
    bf* qbase = qkv + (size_t)n * 57344 + (size_t)g * 7168;
    stage_qk(qbase, aq, bq, g, qT, kT, tid);
    __syncthreads();
    phase1(qT, kT, relTq, relTk, qkl, Sql, Krl, tid);
    __syncthreads();

    // fused sim-combine + softmax (wave per row, lane = j)
    int w = tid >> 6, l = tid & 63;
    float a0 = asim[g], a1 = asim[8 + g], a2 = asim[16 + g];
    float bb = bsim[g] + bsim[8 + g] + bsim[16 + g];
    for (int rr = 0; rr < 7; ++rr) {
        int i = w * 7 + rr;
        int j = l;
        bool valid = j < 56;
        float sc = -1e30f;
        if (valid)
            sc = a0 * qkl[i * 57 + j] + a1 * Sql[i * 112 + (i - j + 55)]
               + a2 * Krl[j * 112 + (j - i + 55)] + bb;
        float mx = sc;
#pragma unroll
        for (int off = 32; off; off >>= 1) mx = fmaxf(mx, __shfl_xor(mx, off));
        float p = valid ? __expf(sc - mx) : 0.f;
        float su = p;
#pragma unroll
        for (int off = 32; off; off >>= 1) su += __shfl_xor(su, off);
        if (valid) qkl[i * 57 + j] = p / su;
    }
    __syncthreads();

    // phase-2 builds: vB (affine v), simB (p bf16, j-padded 0), Pb (skewed p, padded 0)
    for (int u = tid; u < 448; u += 512) {
        int c = u / 7, ch = u - c * 7;
        int o = g * 128 + 64 + c;
        float a = aq[o], b = bq[o];
        bf16x8 raw = *reinterpret_cast<const bf16x8*>(qbase + (64 + c) * 56 + ch * 8);
        bf16x8 out;
#pragma unroll
        for (int u8 = 0; u8 < 8; ++u8) out[u8] = f2bfbits(a * bfbits2f(raw[u8]) + b);
        *reinterpret_cast<bf16x8*>(&vB[c * 64 + ch * 8]) = out;
    }
    if (tid < 512) vB[(tid >> 3) * 64 + 56 + (tid & 7)] = 0;
    for (int e = tid; e < 3584; e += 512) {
        int i = e >> 6, j = e & 63;
        simB[i * 64 + j] = f2bfbits((j < 56) ? qkl[i * 57 + j] : 0.f);
    }
    for (int e = tid; e < 7168; e += 512) {
        int i = e >> 7, d = e & 127;
        int jj = i - d + 55;
        Pb[i * 128 + d] = f2bfbits((jj >= 0 && jj < 56) ? qkl[i * 57 + jj] : 0.f);
    }
    __syncthreads();

    // phase 2: sv = v . sim^T ; sve = rel_v . P^T
    int m = w >> 1, s = w & 1, la = l & 15, lb = l >> 4;
    f32x4 sva[2]  = {{0,0,0,0},{0,0,0,0}};
    f32x4 svea[2] = {{0,0,0,0},{0,0,0,0}};
#pragma unroll
    for (int ks = 0; ks < 2; ++ks) {
        bf16x8 av = *reinterpret_cast<const bf16x8*>(&vB[(m * 16 + la) * 64 + ks * 32 + lb * 8]);
#pragma unroll
        for (int t = 0; t < 2; ++t) {
            int nt = 2 * s + t;
            bf16x8 bs = *reinterpret_cast<const bf16x8*>(&simB[(nt * 16 + la) * 64 + ks * 32 + lb * 8]);
            sva[t] = MFMA16(av, bs, sva[t]);
        }
    }
#pragma unroll
    for (int ks = 0; ks < 4; ++ks) {
        bf16x8 ar = *reinterpret_cast<const bf16x8*>(&relBv[(m * 16 + la) * 128 + ks * 32 + lb * 8]);
#pragma unroll
        for (int t = 0; t < 2; ++t) {
            int nt = 2 * s + t;
            bf16x8 bp = *reinterpret_cast<const bf16x8*>(&Pb[(nt * 16 + la) * 128 + ks * 32 + lb * 8]);
            svea[t] = MFMA16(ar, bp, svea[t]);
        }
    }
    // write packed (sv,sve) bf16 pairs over own slice + out-BN stats
    uint32_t* svz = reinterpret_cast<uint32_t*>(qbase);
    float st0[4] = {0,0,0,0}, st1[4] = {0,0,0,0}, st2[4] = {0,0,0,0}, st3[4] = {0,0,0,0};
#pragma unroll
    for (int t = 0; t < 2; ++t) {
        int i = (2 * s + t) * 16 + la;
        bool ok = i < 56;
#pragma unroll
        for (int r = 0; r < 4; ++r) {
            int c = m * 16 + lb * 4 + r;
            float va = sva[t][r], ve = svea[t][r];
            if (ok) {
                svz[c * 56 + i] = ((uint32_t)(unsigned short)f2bfbits(va)) |
                                  (((uint32_t)(unsigned short)f2bfbits(ve)) << 16);
                st0[r] += va; st1[r] += va * va; st2[r] += ve; st3[r] += ve * ve;
            }
        }
    }
#pragma unroll
    for (int r = 0; r < 4; ++r) {
#pragma unroll
        for (int mk = 1; mk < 16; mk <<= 1) {
            st0[r] += __shfl_xor(st0[r], mk);
            st1[r] += __shfl_xor(st1[r], mk);
            st2[r] += __shfl_xor(st2[r], mk);
            st3[r] += __shfl_xor(st3[r], mk);
        }
    }
    if (la == 0) {
#pragma unroll
        for (int r = 0; r < 4; ++r) {
            int c = m * 16 + lb * 4 + r;
            red[(0 * 64 + c) * 2 + s] = st0[r];
            red[(1 * 64 + c) * 2 + s] = st1[r];
            red[(2 * 64 + c) * 2 + s] = st2[r];
            red[(3 * 64 + c) * 2 + s] = st3[r];
        }
    }
    __syncthreads();
    if (tid < 64) {
        int c = tid, o2 = (g * 64 + c) * 2, bkt = blk & 7;
        atomicAdd(&osum[o2 * 8 + bkt],       red[(0 * 64 + c) * 2] + red[(0 * 64 + c) * 2 + 1]);
        atomicAdd(&osq [o2 * 8 + bkt],       red[(1 * 64 + c) * 2] + red[(1 * 64 + c) * 2 + 1]);
        atomicAdd(&osum[(o2 + 1) * 8 + bkt], red[(2 * 64 + c) * 2] + red[(2 * 64 + c) * 2 + 1]);
        atomicAdd(&osq [(o2 + 1) * 8 + bkt], red[(3 * 64 + c) * 2] + red[(3 * 64 + c) * 2 + 1]);
    }
}

__global__ __launch_bounds__(256) void k3b_coef(const float* __restrict__ osum, const float* __restrict__ osq,
                                                const float* __restrict__ go, const float* __restrict__ bo,
                                                float* __restrict__ a_c, float* __restrict__ b_c) {
    int o = blockIdx.x * 256 + threadIdx.x;
    float s = 0, s2 = 0;
#pragma unroll
    for (int k = 0; k < 8; ++k) { s += osum[o * 8 + k]; s2 += osq[o * 8 + k]; }
    float inv = 1.f / 50176.f;
    float mean = s * inv;
    float var = s2 * inv - mean * mean;
    float a = go[o] * rsqrtf(var + EPS);
    a_c[o] = a; b_c[o] = bo[o] - a * mean;
}

// ---------------- K4: out BN + pair-sum + transpose to (B,OUT,T,H,W) ----------------
__global__ __launch_bounds__(256) void k4_out(const uint32_t* __restrict__ svz,
                                              const float* __restrict__ ao, const float* __restrict__ bo,
                                              float* __restrict__ out) {
    int blk = blockIdx.x;
    int oc = blk & 511, bt = blk >> 9;
    int b = bt >> 2, tt = bt & 3;
    int g = oc >> 6, c = oc & 63;
    __shared__ float tile[56][57];
    int tid = threadIdx.x;
    int o_sv = oc * 2, o_sve = oc * 2 + 1;
    float asv = ao[o_sv], bsv = bo[o_sv], asve = ao[o_sve], bsve = bo[o_sve];
    float badd = bsv + bsve;
    int nbase = (b * 4 + tt) * 56;
    for (int e = tid; e < 3136; e += 256) {
        int wq = e / 56, h = e - wq * 56;
        size_t idx = (size_t)(nbase + wq) * 28672 + (size_t)g * 3584 + c * 56 + h;
        union { uint32_t u; unsigned short hh[2]; } pk;
        pk.u = svz[idx];
        tile[wq][h] = asv * bfbits2f((short)pk.hh[0]) + asve * bfbits2f((short)pk.hh[1]) + badd;
    }
    __syncthreads();
    size_t ob = ((size_t)(b * 512 + oc) * 4 + tt) * 3136;
    for (int e = tid; e < 3136; e += 256) {
        int h = e / 56, wq = e - h * 56;
        out[ob + h * 56 + wq] = tile[wq][h];
    }
}

extern "C" void kernel_launch(void* const* d_in, const int* in_sizes, int n_in,
                              void* d_out, int out_size, void* d_ws, size_t ws_size,
                              hipStream_t stream) {
    (void)in_sizes; (void)n_in; (void)out_size; (void)ws_size;
    const float* x     = (const float*)d_in[0];
    const float* w_qkv = (const float*)d_in[1];
    const float* g_qkv = (const float*)d_in[2];
    const float* b_qkv = (const float*)d_in[3];
    const float* rel   = (const float*)d_in[4];
    const float* g_sim = (const float*)d_in[5];
    const float* b_sim = (const float*)d_in[6];
    const float* g_out = (const float*)d_in[7];
    const float* b_out = (const float*)d_in[8];
    float* ws  = (float*)d_ws;
    float* out = (float*)d_out;
    bf*    qkv = (bf*)(ws + WS_QKV_F);
    bf*    xbt = (bf*)d_out;                       // [50176][512] bf16, dead after k1
    bf*    wb  = (bf*)((char*)d_out + 51380224);   // [1024][512] bf16
    short* relTq = (short*)((char*)d_ws + RELTQ_B);
    short* relTk = (short*)((char*)d_ws + RELTK_B);
    short* relBv = (short*)((char*)d_ws + RELBV_B);

    hipMemsetAsync(ws, 0, WS_ZERO_END * sizeof(float), stream);
    k0_transpose<<<896, 256, 0, stream>>>(x, xbt);
    kw_conv<<<512, 256, 0, stream>>>(w_qkv, wb);
    kprep<<<46, 256, 0, stream>>>(rel, relTq, relTk, relBv);
    k1_mfma<<<dim3(448, 8), 256, 0, stream>>>(xbt, wb, qkv);
    k1b_stats<<<1024, 256, 0, stream>>>(qkv, g_qkv, b_qkv, ws + WS_AQKV, ws + WS_BQKV);
    k2_mfma<<<7168, 512, 0, stream>>>(qkv, relTq, relTk, ws + WS_AQKV, ws + WS_BQKV,
                                      ws + WS_SIMSUM, ws + WS_SIMSQ);
    k2b_coef<<<1, 64, 0, stream>>>(ws + WS_SIMSUM, ws + WS_SIMSQ, g_sim, b_sim,
                                   ws + WS_ASIM, ws + WS_BSIM);
    k3_mfma<<<7168, 512, 0, stream>>>(qkv, relTq, relTk, relBv,
                                      ws + WS_AQKV, ws + WS_BQKV,
                                      ws + WS_ASIM, ws + WS_BSIM,
                                      ws + WS_OUTSUM, ws + WS_OUTSQ);
    k3b_coef<<<4, 256, 0, stream>>>(ws + WS_OUTSUM, ws + WS_OUTSQ, g_out, b_out,
                                    ws + WS_AOUT, ws + WS_BOUT);
    k4_out<<<8192, 256, 0, stream>>>((const uint32_t*)qkv, ws + WS_AOUT, ws + WS_BOUT, out);
}

// Round 5
// 571.657 us; speedup vs baseline: 3.0826x; 1.0180x over previous
//
#include <hip/hip_runtime.h>
#include <hip/hip_bf16.h>

#define EPS 1e-5f
typedef __hip_bfloat16 bf;
typedef __attribute__((ext_vector_type(8))) short bf16x8;
typedef __attribute__((ext_vector_type(4))) float f32x4;

#define MFMA16(a, b, c) __builtin_amdgcn_mfma_f32_16x16x32_bf16(a, b, c, 0, 0, 0)

// Sizes: B=4, C_IN=512, T=4, H=W=K=56, G=8, GP=64, OCH=1024 ; NB=896 ; NP=50176
// ---- ws float offsets ----
#define WS_QSUM     0        // [1024][4]
#define WS_QSQ      4096
#define WS_SIMSUM   8192     // [24][64]
#define WS_SIMSQ    9728
#define WS_OUTSUM   11264    // [1024][8]
#define WS_OUTSQ    19456
#define WS_ZERO_END 27648
#define WS_AQKV     27648
#define WS_BQKV     28672
#define WS_ASIM     29696
#define WS_BSIM     29728
#define WS_AOUT     29760
#define WS_BOUT     30784
#define WS_QKV_F    32768    // qkv bf16 [896][1024][56] @ byte 131072 (total = 102,891,520 B, proven)
// ---- d_out scratch ----
// phase A (k0..k1): xbt bf16 [50176][512] @0 (51.4MB); wb bf16 [1024][512] @51,380,224
// kprep: relTq [112][32] @73,400,320 ; relTk @73,407,488 ; relBv [64][128] @73,414,656
// phase B (kbn..k3): qkT bf16 [896][8][2][64][40] @0 (73.4MB). k4 overwrites d_out with final.

__device__ __forceinline__ void gload_lds16(const void* g, void* l) {
    __builtin_amdgcn_global_load_lds(
        (const __attribute__((address_space(1))) void*)g,
        (__attribute__((address_space(3))) void*)l, 16, 0, 0);
}
__device__ __forceinline__ float bfbits2f(short b) {
    return __uint_as_float(((uint32_t)(unsigned short)b) << 16);
}
__device__ __forceinline__ short f2bfbits(float f) {
    return (short)__hip_bfloat16_raw(__float2bfloat16(f)).x;
}

// ---------------- K0: x (B,C,T,H,W) f32 -> xbt[p][c] bf16, p = ((b*4+t)*56+w)*56+h ----------------
__global__ __launch_bounds__(256) void k0_transpose(const float* __restrict__ x,
                                                    bf* __restrict__ xbt) {
    int bid = blockIdx.x;                // ((b*4+t)*56 + h)
    int h = bid % 56, bt = bid / 56;
    int b = bt >> 2, t = bt & 3;
    __shared__ short tile[512 * 57];
    const float* src = x + (((size_t)(b * 512) * 4 + t) * 3136) + h * 56;
    for (int e = threadIdx.x; e < 512 * 56; e += 256) {
        int c = e / 56, w = e - c * 56;
        tile[c * 57 + w] = f2bfbits(src[(size_t)c * 12544 + w]);
    }
    __syncthreads();
    short* dst = reinterpret_cast<short*>(xbt);
    size_t pbase = ((size_t)bt * 56) * 56 + h;
    for (int e = threadIdx.x; e < 512 * 56; e += 256) {
        int w = e >> 9, c = e & 511;
        dst[(pbase + (size_t)w * 56) * 512 + c] = tile[c * 57 + w];
    }
}

// ---------------- KW: w f32 [1024][512] -> bf16 ----------------
__global__ __launch_bounds__(256) void kw_conv(const float* __restrict__ w, bf* __restrict__ wb) {
    int i = (blockIdx.x * 256 + threadIdx.x) * 4;
#pragma unroll
    for (int u = 0; u < 4; ++u) wb[i + u] = __float2bfloat16(w[i + u]);
}

// ---------------- KPREP: rel f32 -> relTq/relTk [112][32], relBv [64][128] bf16 ----------------
__global__ __launch_bounds__(256) void kprep(const float* __restrict__ rel,
                                             short* __restrict__ relTq,
                                             short* __restrict__ relTk,
                                             short* __restrict__ relBv) {
    int tid = blockIdx.x * 256 + threadIdx.x;
    if (tid < 3584) {
        int d = tid >> 5, c = tid & 31;
        relTq[tid] = f2bfbits(d < 111 ? rel[c * 111 + d] : 0.f);
        relTk[tid] = f2bfbits(d < 111 ? rel[(32 + c) * 111 + d] : 0.f);
    } else if (tid < 11776) {
        int u = tid - 3584, c = u >> 7, d = u & 127;
        relBv[u] = f2bfbits(d < 111 ? rel[(64 + c) * 111 + d] : 0.f);
    }
}

// ---------------- K1: MFMA GEMM + in-register qkv BN partial stats ----------------
__global__ __launch_bounds__(256) void k1_mfma(const bf* __restrict__ xbt,
                                               const bf* __restrict__ wb,
                                               bf* __restrict__ qkv,
                                               float* __restrict__ qsum,
                                               float* __restrict__ qsq) {
    __shared__ short As[128 * 64];
    __shared__ short Bs[112 * 64];
    int tid = threadIdx.x;
    int p0 = blockIdx.x * 112;
    int o0 = blockIdx.y * 128;
    const short* aG = reinterpret_cast<const short*>(wb);
    const short* bG = reinterpret_cast<const short*>(xbt);
    int wv = tid >> 6, l = tid & 63, r16 = l & 15, q4 = l >> 4;

    f32x4 acc[2][7];
#pragma unroll
    for (int i = 0; i < 2; ++i)
#pragma unroll
        for (int j = 0; j < 7; ++j) acc[i][j] = (f32x4){0.f, 0.f, 0.f, 0.f};

    const short* aBase = &As[(wv * 32 + r16) * 64 + q4 * 8];
    const short* bBase = &Bs[r16 * 64 + q4 * 8];

    for (int k0 = 0; k0 < 512; k0 += 64) {
        int ch = tid;
#pragma unroll
        for (int it = 0; it < 4; ++it, ch += 256) {
            int row = ch >> 3, c8 = (ch & 7) << 3;
            gload_lds16(aG + (((size_t)(o0 + row)) << 9) + k0 + c8, &As[ch << 3]);
        }
        ch = tid;
#pragma unroll
        for (int it = 0; it < 3; ++it, ch += 256) {
            int row = ch >> 3, c8 = (ch & 7) << 3;
            gload_lds16(bG + (((size_t)(p0 + row)) << 9) + k0 + c8, &Bs[ch << 3]);
        }
        if (tid < 128) {
            int row = (tid + 768) >> 3, c8 = (tid & 7) << 3;
            gload_lds16(bG + (((size_t)(p0 + row)) << 9) + k0 + c8, &Bs[(tid + 768) << 3]);
        }
        __syncthreads();
#pragma unroll
        for (int kk = 0; kk < 2; ++kk) {
            bf16x8 a0 = *reinterpret_cast<const bf16x8*>(aBase + kk * 32);
            bf16x8 a1 = *reinterpret_cast<const bf16x8*>(aBase + 16 * 64 + kk * 32);
#pragma unroll
            for (int j = 0; j < 7; ++j) {
                bf16x8 bj = *reinterpret_cast<const bf16x8*>(bBase + j * 16 * 64 + kk * 32);
                acc[0][j] = MFMA16(a0, bj, acc[0][j]);
                acc[1][j] = MFMA16(a1, bj, acc[1][j]);
            }
        }
        __syncthreads();
    }
    // per-channel partial stats (f32, pre-rounding): reduce over j-tiles + 16 p-lanes
    int bkt = blockIdx.x & 3;
#pragma unroll
    for (int i = 0; i < 2; ++i)
#pragma unroll
        for (int r = 0; r < 4; ++r) {
            float sA = 0.f, sB = 0.f;
#pragma unroll
            for (int j = 0; j < 7; ++j) { float v = acc[i][j][r]; sA += v; sB += v * v; }
#pragma unroll
            for (int mk = 1; mk < 16; mk <<= 1) { sA += __shfl_xor(sA, mk); sB += __shfl_xor(sB, mk); }
            if (r16 == 0) {
                int o = o0 + wv * 32 + i * 16 + q4 * 4 + r;
                atomicAdd(&qsum[o * 4 + bkt], sA);
                atomicAdd(&qsq [o * 4 + bkt], sB);
            }
        }
#pragma unroll
    for (int j = 0; j < 7; ++j) {
        int p = p0 + j * 16 + r16;
        int n = p / 56, h = p - n * 56;
        size_t nb = (size_t)n * 57344 + h;
#pragma unroll
        for (int i = 0; i < 2; ++i) {
            int ob = o0 + wv * 32 + i * 16 + q4 * 4;
#pragma unroll
            for (int r = 0; r < 4; ++r)
                qkv[nb + (size_t)(ob + r) * 56] = __float2bfloat16(acc[i][j][r]);
        }
    }
}

// ---------------- K1b: bucket reduce -> qkv BN coeffs ----------------
__global__ __launch_bounds__(256) void k1b_coef(const float* __restrict__ qsum, const float* __restrict__ qsq,
                                                const float* __restrict__ gamma, const float* __restrict__ beta,
                                                float* __restrict__ a_c, float* __restrict__ b_c) {
    int o = blockIdx.x * 256 + threadIdx.x;
    float s = qsum[o * 4] + qsum[o * 4 + 1] + qsum[o * 4 + 2] + qsum[o * 4 + 3];
    float s2 = qsq[o * 4] + qsq[o * 4 + 1] + qsq[o * 4 + 2] + qsq[o * 4 + 3];
    float inv = 1.f / 50176.f;
    float mean = s * inv;
    float var = s2 * inv - mean * mean;
    float a = gamma[o] * rsqrtf(var + EPS);
    a_c[o] = a; b_c[o] = beta[o] - a * mean;
}

// ---------------- KBN: apply BN affine to q,k and write transposed qkT[n][g][2][64][40] ----------------
__global__ __launch_bounds__(256) void kbn(const bf* __restrict__ qkv,
                                           const float* __restrict__ aq, const float* __restrict__ bq,
                                           short* __restrict__ qkT) {
    int blk = blockIdx.x, n = blk >> 3, g = blk & 7, tid = threadIdx.x;
    __shared__ short tl[64 * 64];   // [c 0..63][i stride 64]
    const bf* src = qkv + (size_t)n * 57344 + (size_t)g * 7168;
    for (int u = tid; u < 448; u += 256) {
        int c = u / 7, ch = u - c * 7;
        int o = g * 128 + c;
        float a = aq[o], b = bq[o];
        bf16x8 raw = *reinterpret_cast<const bf16x8*>(src + c * 56 + ch * 8);
        bf16x8 t;
#pragma unroll
        for (int u8 = 0; u8 < 8; ++u8) t[u8] = f2bfbits(a * bfbits2f(raw[u8]) + b);
        *reinterpret_cast<bf16x8*>(&tl[c * 64 + ch * 8]) = t;
    }
    __syncthreads();
    short* dst = qkT + (size_t)(n * 8 + g) * 5120;
    for (int u = tid; u < 448; u += 256) {
        int part = u / 224, rem = u - part * 224;
        int i = rem >> 2, c0 = (rem & 3) * 8;
        bf16x8 t;
#pragma unroll
        for (int u8 = 0; u8 < 8; ++u8) t[u8] = tl[(part * 32 + c0 + u8) * 64 + i];
        *reinterpret_cast<bf16x8*>(&dst[part * 2560 + i * 40 + c0]) = t;
    }
}

// ---------------- K2: sim BN stats fully in registers ----------------
__global__ __launch_bounds__(512, 6) void k2_mfma(const short* __restrict__ qkT,
                                                  const short* __restrict__ relTq,
                                                  const short* __restrict__ relTk,
                                                  float* __restrict__ ssum, float* __restrict__ ssq) {
    __shared__ __align__(16) short qkTl[5120];
    __shared__ float red[48];
    int blk = blockIdx.x, n = blk >> 3, g = blk & 7, tid = threadIdx.x;
    const short* gsl = qkT + (size_t)(n * 8 + g) * 5120;
    for (int ch = tid; ch < 640; ch += 512)
        gload_lds16(gsl + ch * 8, &qkTl[ch * 8]);
    __syncthreads();

    int w = tid >> 6, l = tid & 63, m = w >> 1, s = w & 1, la = l & 15, lb = l >> 4;
    bf16x8 aqf = *reinterpret_cast<const bf16x8*>(&qkTl[(m * 16 + la) * 40 + lb * 8]);
    bf16x8 akf = *reinterpret_cast<const bf16x8*>(&qkTl[(64 + m * 16 + la) * 40 + lb * 8]);
    float s0 = 0, s1 = 0, s2v = 0, q0 = 0, q1 = 0, q2 = 0;
#pragma unroll
    for (int t = 0; t < 2; ++t) {
        int nt = 2 * s + t;
        bf16x8 bk = *reinterpret_cast<const bf16x8*>(&qkTl[(64 + nt * 16 + la) * 40 + lb * 8]);
        f32x4 acc = {0, 0, 0, 0};
        acc = MFMA16(aqf, bk, acc);
        int j = nt * 16 + la;
        if (j < 56) {
#pragma unroll
            for (int r = 0; r < 4; ++r) {
                int i = m * 16 + lb * 4 + r;
                if (i < 56) { float v = acc[r]; s0 += v; q0 += v * v; }
            }
        }
    }
    int ndt = s ? 3 : 4, dt0 = s * 4;
    for (int t = 0; t < ndt; ++t) {
        int dt = dt0 + t;
        bf16x8 br = *reinterpret_cast<const bf16x8*>(relTq + (dt * 16 + la) * 32 + lb * 8);
        f32x4 acc = {0, 0, 0, 0};
        acc = MFMA16(aqf, br, acc);
        int d = dt * 16 + la;
#pragma unroll
        for (int r = 0; r < 4; ++r) {
            int i = m * 16 + lb * 4 + r;
            if (i < 56 && d >= i && d <= i + 55) { float v = acc[r]; s1 += v; q1 += v * v; }
        }
    }
    for (int t = 0; t < ndt; ++t) {
        int dt = dt0 + t;
        bf16x8 br = *reinterpret_cast<const bf16x8*>(relTk + (dt * 16 + la) * 32 + lb * 8);
        f32x4 acc = {0, 0, 0, 0};
        acc = MFMA16(akf, br, acc);
        int d = dt * 16 + la;
#pragma unroll
        for (int r = 0; r < 4; ++r) {
            int j = m * 16 + lb * 4 + r;
            if (j < 56 && d >= j && d <= j + 55) { float v = acc[r]; s2v += v; q2 += v * v; }
        }
    }
    float vals[6] = {s0, s1, s2v, q0, q1, q2};
#pragma unroll
    for (int v = 0; v < 6; ++v) {
        for (int off = 32; off; off >>= 1) vals[v] += __shfl_down(vals[v], off);
        if (l == 0) red[v * 8 + w] = vals[v];
    }
    __syncthreads();
    if (tid < 6) {
        float tot = 0;
#pragma unroll
        for (int k = 0; k < 8; ++k) tot += red[tid * 8 + k];
        int comp = (tid < 3) ? tid : tid - 3;
        int ch = comp * 8 + g;
        int bkt = blk & 63;
        atomicAdd((tid < 3 ? ssum : ssq) + ch * 64 + bkt, tot);
    }
}

__global__ void k2b_coef(const float* __restrict__ ssum, const float* __restrict__ ssq,
                         const float* __restrict__ gs, const float* __restrict__ bs,
                         float* __restrict__ a_c, float* __restrict__ b_c) {
    int c = threadIdx.x;
    if (c >= 24) return;
    float s = 0, s2 = 0;
    for (int k = 0; k < 64; ++k) { s += ssum[c * 64 + k]; s2 += ssq[c * 64 + k]; }
    float inv = 1.f / 2809856.f;
    float mean = s * inv;
    float var = s2 * inv - mean * mean;
    float a = gs[c] * rsqrtf(var + EPS);
    a_c[c] = a; b_c[c] = bs[c] - a * mean;
}

// ---------------- K3: attention core (gload staging, reg softmax, padded LDS) ----------------
__global__ __launch_bounds__(512, 6) void k3_mfma(bf* __restrict__ qkv,
                                                  const short* __restrict__ qkT,
                                                  const short* __restrict__ relTq,
                                                  const short* __restrict__ relTk,
                                                  const short* __restrict__ relBv,
                                                  const float* __restrict__ aq, const float* __restrict__ bq,
                                                  const float* __restrict__ asim, const float* __restrict__ bsim,
                                                  float* __restrict__ osum, float* __restrict__ osq) {
    __shared__ __align__(16) char smem[51680];
    short* qkTl = (short*)smem;                 // [2][64][40] 10240B ; phase2: vB [64][72]
    float* qkl  = (float*)(smem + 10240);       // [56][57] f32
    short* Sql  = (short*)(smem + 23008);       // [56][112] bf16
    short* Krl  = (short*)(smem + 35552);       // [56][112] bf16
    short* simB = (short*)(smem + 23008);       // phase2 overlay [64][72]
    short* Pb   = (short*)(smem + 32224);       // phase2 overlay [64][136]
    short* vBl  = (short*)smem;
    float* red  = (float*)(smem + 49632);

    int blk = blockIdx.x, n = blk >> 3, g = blk & 7, tid = threadIdx.x;
    const short* gsl = qkT + (size_t)(n * 8 + g) * 5120;
    for (int ch = tid; ch < 640; ch += 512)
        gload_lds16(gsl + ch * 8, &qkTl[ch * 8]);
    __syncthreads();

    int w = tid >> 6, l = tid & 63, m = w >> 1, s = w & 1, la = l & 15, lb = l >> 4;
    {
        bf16x8 aqf = *reinterpret_cast<const bf16x8*>(&qkTl[(m * 16 + la) * 40 + lb * 8]);
        bf16x8 akf = *reinterpret_cast<const bf16x8*>(&qkTl[(64 + m * 16 + la) * 40 + lb * 8]);
#pragma unroll
        for (int t = 0; t < 2; ++t) {
            int nt = 2 * s + t;
            bf16x8 bk = *reinterpret_cast<const bf16x8*>(&qkTl[(64 + nt * 16 + la) * 40 + lb * 8]);
            f32x4 acc = {0, 0, 0, 0};
            acc = MFMA16(aqf, bk, acc);
            int j = nt * 16 + la;
            if (j < 56) {
#pragma unroll
                for (int r = 0; r < 4; ++r) {
                    int i = m * 16 + lb * 4 + r;
                    if (i < 56) qkl[i * 57 + j] = acc[r];
                }
            }
        }
        int ndt = s ? 3 : 4, dt0 = s * 4;
        for (int t = 0; t < ndt; ++t) {
            int dt = dt0 + t;
            bf16x8 br = *reinterpret_cast<const bf16x8*>(relTq + (dt * 16 + la) * 32 + lb * 8);
            f32x4 acc = {0, 0, 0, 0};
            acc = MFMA16(aqf, br, acc);
            int d = dt * 16 + la;
#pragma unroll
            for (int r = 0; r < 4; ++r) {
                int i = m * 16 + lb * 4 + r;
                if (i < 56) Sql[i * 112 + d] = f2bfbits(acc[r]);
            }
        }
        for (int t = 0; t < ndt; ++t) {
            int dt = dt0 + t;
            bf16x8 br = *reinterpret_cast<const bf16x8*>(relTk + (dt * 16 + la) * 32 + lb * 8);
            f32x4 acc = {0, 0, 0, 0};
            acc = MFMA16(akf, br, acc);
            int d = dt * 16 + la;
#pragma unroll
            for (int r = 0; r < 4; ++r) {
                int j = m * 16 + lb * 4 + r;
                if (j < 56) Krl[j * 112 + d] = f2bfbits(acc[r]);
            }
        }
    }
    __syncthreads();

    // combine + softmax into regs; stage vB (affine) into dead qkT region
    bf* qbase = qkv + (size_t)n * 57344 + (size_t)g * 7168;
    for (int u = tid; u < 448; u += 512) {
        int c = u / 7, ch = u - c * 7;
        int o = g * 128 + 64 + c;
        float a = aq[o], b = bq[o];
        bf16x8 raw = *reinterpret_cast<const bf16x8*>(qbase + (64 + c) * 56 + ch * 8);
        bf16x8 outv;
#pragma unroll
        for (int u8 = 0; u8 < 8; ++u8) outv[u8] = f2bfbits(a * bfbits2f(raw[u8]) + b);
        *reinterpret_cast<bf16x8*>(&vBl[c * 72 + ch * 8]) = outv;
    }
    if (tid < 128) {
        int c = tid >> 1, chp = tid & 1;
        bf16x8 z = {0, 0, 0, 0, 0, 0, 0, 0};
        *reinterpret_cast<bf16x8*>(&vBl[c * 72 + 56 + chp * 8]) = z;
    }
    float a0 = asim[g], a1 = asim[8 + g], a2 = asim[16 + g];
    float bb = bsim[g] + bsim[8 + g] + bsim[16 + g];
    float p[7];
#pragma unroll
    for (int rr = 0; rr < 7; ++rr) {
        int i = w * 7 + rr;
        float sc = -1e30f;
        if (l < 56) {
            sc = a0 * qkl[i * 57 + l]
               + a1 * bfbits2f(Sql[i * 112 + (i - l + 55)])
               + a2 * bfbits2f(Krl[l * 112 + (l - i + 55)]) + bb;
        }
        float mx = sc;
#pragma unroll
        for (int off = 32; off; off >>= 1) mx = fmaxf(mx, __shfl_xor(mx, off));
        float e = (l < 56) ? __expf(sc - mx) : 0.f;
        float su = e;
#pragma unroll
        for (int off = 32; off; off >>= 1) su += __shfl_xor(su, off);
        p[rr] = e / su;
    }
    __syncthreads();   // region3 reads done

#pragma unroll
    for (int rr = 0; rr < 7; ++rr) {
        int i = w * 7 + rr;
        short pv = f2bfbits(p[rr]);
        simB[i * 72 + l] = (l < 56) ? pv : (short)0;
        if (l < 56) Pb[i * 136 + (i - l + 55)] = pv;
        if (l < i || l > i + 55) Pb[i * 136 + l] = 0;
        if (l > i - 9) Pb[i * 136 + l + 64] = 0;
        if (l < 8) Pb[i * 136 + l + 128] = 0;
    }
    __syncthreads();

    // phase 2: sv = v . P^T ; sve = rel_v . Pskew^T
    f32x4 sva[2]  = {{0, 0, 0, 0}, {0, 0, 0, 0}};
    f32x4 svea[2] = {{0, 0, 0, 0}, {0, 0, 0, 0}};
#pragma unroll
    for (int ks = 0; ks < 2; ++ks) {
        bf16x8 av = *reinterpret_cast<const bf16x8*>(&vBl[(m * 16 + la) * 72 + ks * 32 + lb * 8]);
#pragma unroll
        for (int t = 0; t < 2; ++t) {
            int nt = 2 * s + t;
            bf16x8 bsf = *reinterpret_cast<const bf16x8*>(&simB[(nt * 16 + la) * 72 + ks * 32 + lb * 8]);
            sva[t] = MFMA16(av, bsf, sva[t]);
        }
    }
#pragma unroll
    for (int ks = 0; ks < 4; ++ks) {
        bf16x8 ar = *reinterpret_cast<const bf16x8*>(relBv + (m * 16 + la) * 128 + ks * 32 + lb * 8);
#pragma unroll
        for (int t = 0; t < 2; ++t) {
            int nt = 2 * s + t;
            bf16x8 bp = *reinterpret_cast<const bf16x8*>(&Pb[(nt * 16 + la) * 136 + ks * 32 + lb * 8]);
            svea[t] = MFMA16(ar, bp, svea[t]);
        }
    }
    // write packed (sv,sve) pairs over own q/k slice + out-BN partial stats
    uint32_t* svz = reinterpret_cast<uint32_t*>(qbase);
    float st0[4] = {0, 0, 0, 0}, st1[4] = {0, 0, 0, 0}, st2[4] = {0, 0, 0, 0}, st3[4] = {0, 0, 0, 0};
#pragma unroll
    for (int t = 0; t < 2; ++t) {
        int i = (2 * s + t) * 16 + la;
        bool ok = i < 56;
#pragma unroll
        for (int r = 0; r < 4; ++r) {
            int c = m * 16 + lb * 4 + r;
            float va = sva[t][r], ve = svea[t][r];
            if (ok) {
                svz[c * 56 + i] = ((uint32_t)(unsigned short)f2bfbits(va)) |
                                  (((uint32_t)(unsigned short)f2bfbits(ve)) << 16);
                st0[r] += va; st1[r] += va * va; st2[r] += ve; st3[r] += ve * ve;
            }
        }
    }
#pragma unroll
    for (int r = 0; r < 4; ++r) {
#pragma unroll
        for (int mk = 1; mk < 16; mk <<= 1) {
            st0[r] += __shfl_xor(st0[r], mk);
            st1[r] += __shfl_xor(st1[r], mk);
            st2[r] += __shfl_xor(st2[r], mk);
            st3[r] += __shfl_xor(st3[r], mk);
        }
    }
    if (la == 0) {
#pragma unroll
        for (int r = 0; r < 4; ++r) {
            int c = m * 16 + lb * 4 + r;
            red[(0 * 64 + c) * 2 + s] = st0[r];
            red[(1 * 64 + c) * 2 + s] = st1[r];
            red[(2 * 64 + c) * 2 + s] = st2[r];
            red[(3 * 64 + c) * 2 + s] = st3[r];
        }
    }
    __syncthreads();
    if (tid < 64) {
        int c = tid, o2 = (g * 64 + c) * 2, bkt = blk & 7;
        atomicAdd(&osum[o2 * 8 + bkt],       red[(0 * 64 + c) * 2] + red[(0 * 64 + c) * 2 + 1]);
        atomicAdd(&osq [o2 * 8 + bkt],       red[(1 * 64 + c) * 2] + red[(1 * 64 + c) * 2 + 1]);
        atomicAdd(&osum[(o2 + 1) * 8 + bkt], red[(2 * 64 + c) * 2] + red[(2 * 64 + c) * 2 + 1]);
        atomicAdd(&osq [(o2 + 1) * 8 + bkt], red[(3 * 64 + c) * 2] + red[(3 * 64 + c) * 2 + 1]);
    }
}

__global__ __launch_bounds__(256) void k3b_coef(const float* __restrict__ osum, const float* __restrict__ osq,
                                                const float* __restrict__ go, const float* __restrict__ bo,
                                                float* __restrict__ a_c, float* __restrict__ b_c) {
    int o = blockIdx.x * 256 + threadIdx.x;
    float s = 0, s2 = 0;
#pragma unroll
    for (int k = 0; k < 8; ++k) { s += osum[o * 8 + k]; s2 += osq[o * 8 + k]; }
    float inv = 1.f / 50176.f;
    float mean = s * inv;
    float var = s2 * inv - mean * mean;
    float a = go[o] * rsqrtf(var + EPS);
    a_c[o] = a; b_c[o] = bo[o] - a * mean;
}

// ---------------- K4: out BN + pair-sum + transpose to (B,OUT,T,H,W) ----------------
__global__ __launch_bounds__(256) void k4_out(const uint32_t* __restrict__ svz,
                                              const float* __restrict__ ao, const float* __restrict__ bo,
                                              float* __restrict__ out) {
    int blk = blockIdx.x;
    int oc = blk & 511, bt = blk >> 9;
    int b = bt >> 2, tt = bt & 3;
    int g = oc >> 6, c = oc & 63;
    __shared__ float tile[56][57];
    int tid = threadIdx.x;
    int o_sv = oc * 2, o_sve = oc * 2 + 1;
    float asv = ao[o_sv], bsv = bo[o_sv], asve = ao[o_sve], bsve = bo[o_sve];
    float badd = bsv + bsve;
    int nbase = (b * 4 + tt) * 56;
    for (int e = tid; e < 3136; e += 256) {
        int wq = e / 56, h = e - wq * 56;
        size_t idx = (size_t)(nbase + wq) * 28672 + (size_t)g * 3584 + c * 56 + h;
        union { uint32_t u; unsigned short hh[2]; } pk;
        pk.u = svz[idx];
        tile[wq][h] = asv * bfbits2f((short)pk.hh[0]) + asve * bfbits2f((short)pk.hh[1]) + badd;
    }
    __syncthreads();
    size_t ob = ((size_t)(b * 512 + oc) * 4 + tt) * 3136;
    for (int e = tid; e < 3136; e += 256) {
        int h = e / 56, wq = e - h * 56;
        out[ob + h * 56 + wq] = tile[wq][h];
    }
}

extern "C" void kernel_launch(void* const* d_in, const int* in_sizes, int n_in,
                              void* d_out, int out_size, void* d_ws, size_t ws_size,
                              hipStream_t stream) {
    (void)in_sizes; (void)n_in; (void)out_size; (void)ws_size;
    const float* x     = (const float*)d_in[0];
    const float* w_qkv = (const float*)d_in[1];
    const float* g_qkv = (const float*)d_in[2];
    const float* b_qkv = (const float*)d_in[3];
    const float* rel   = (const float*)d_in[4];
    const float* g_sim = (const float*)d_in[5];
    const float* b_sim = (const float*)d_in[6];
    const float* g_out = (const float*)d_in[7];
    const float* b_out = (const float*)d_in[8];
    float* ws  = (float*)d_ws;
    float* out = (float*)d_out;
    bf*    qkv = (bf*)(ws + WS_QKV_F);
    bf*    xbt = (bf*)d_out;                        // [50176][512] bf16, dead after k1
    bf*    wb  = (bf*)((char*)d_out + 51380224);    // [1024][512] bf16
    short* qkT = (short*)d_out;                     // [896*8][2][64][40] bf16, written by kbn
    short* relTq = (short*)((char*)d_out + 73400320);
    short* relTk = relTq + 3584;
    short* relBv = relTk + 3584;                    // [64][128]

    hipMemsetAsync(ws, 0, WS_ZERO_END * sizeof(float), stream);
    k0_transpose<<<896, 256, 0, stream>>>(x, xbt);
    kw_conv<<<512, 256, 0, stream>>>(w_qkv, wb);
    kprep<<<46, 256, 0, stream>>>(rel, relTq, relTk, relBv);
    k1_mfma<<<dim3(448, 8), 256, 0, stream>>>(xbt, wb, qkv, ws + WS_QSUM, ws + WS_QSQ);
    k1b_coef<<<4, 256, 0, stream>>>(ws + WS_QSUM, ws + WS_QSQ, g_qkv, b_qkv,
                                    ws + WS_AQKV, ws + WS_BQKV);
    kbn<<<7168, 256, 0, stream>>>(qkv, ws + WS_AQKV, ws + WS_BQKV, qkT);
    k2_mfma<<<7168, 512, 0, stream>>>(qkT, relTq, relTk, ws + WS_SIMSUM, ws + WS_SIMSQ);
    k2b_coef<<<1, 64, 0, stream>>>(ws + WS_SIMSUM, ws + WS_SIMSQ, g_sim, b_sim,
                                   ws + WS_ASIM, ws + WS_BSIM);
    k3_mfma<<<7168, 512, 0, stream>>>(qkv, qkT, relTq, relTk, relBv,
                                      ws + WS_AQKV, ws + WS_BQKV,
                                      ws + WS_ASIM, ws + WS_BSIM,
                                      ws + WS_OUTSUM, ws + WS_OUTSQ);
    k3b_coef<<<4, 256, 0, stream>>>(ws + WS_OUTSUM, ws + WS_OUTSQ, g_out, b_out,
                                    ws + WS_AOUT, ws + WS_BOUT);
    k4_out<<<8192, 256, 0, stream>>>((const uint32_t*)qkv, ws + WS_AOUT, ws + WS_BOUT, out);
}